// Round 2
// baseline (395.144 us; speedup 1.0000x reference)
//
#include <hip/hip_runtime.h>
#include <cstdint>
#include <cstddef>

typedef __bf16 bf16;
typedef __bf16 bf16x8 __attribute__((ext_vector_type(8)));
typedef __bf16 bf16x4 __attribute__((ext_vector_type(4)));
typedef float  f32x4  __attribute__((ext_vector_type(4)));

#define EMBED 768
#define FF    3072
#define SEQ   1024
#define BATCH 8
#define ROWS  (BATCH * SEQ)   // 8192

// ---------------- fused prep: 5 weight transposes (fp32 [K][N] -> bf16 [N][K]),
// x -> bf16, rowsum zero.
__global__ void prep_kernel(const float* __restrict__ Wq, const float* __restrict__ Wk,
                            const float* __restrict__ Wv, const float* __restrict__ W1,
                            const float* __restrict__ W2, bf16* __restrict__ WqkvT,
                            bf16* __restrict__ W1T, bf16* __restrict__ W2T,
                            const float* __restrict__ x, bf16* __restrict__ xb,
                            float* __restrict__ rowsum) {
  const int id = blockIdx.x;
  const int tid = threadIdx.x;
  if (id >= 6336) {
    int i = (id - 6336) * 256 + tid;          // float4 chunk of x
    float4 v = ((const float4*)x)[i];
    bf16x4 o;
    o.x = (bf16)v.x; o.y = (bf16)v.y; o.z = (bf16)v.z; o.w = (bf16)v.w;
    ((bf16x4*)xb)[i] = o;
    if (i < ROWS) rowsum[i] = 0.f;
    return;
  }
  __shared__ float tile[32][33];
  const float* src; bf16* dst; int K, N, nbt, kbt;
  if (id < 1728) {
    int w = id / 576, t = id % 576;
    src = (w == 0) ? Wq : (w == 1 ? Wk : Wv);
    dst = WqkvT + (size_t)w * EMBED * EMBED;
    K = EMBED; N = EMBED; nbt = t % 24; kbt = t / 24;
  } else if (id < 4032) {
    int t = id - 1728;
    src = W1; dst = W1T; K = EMBED; N = FF; nbt = t % 96; kbt = t / 96;
  } else {
    int t = id - 4032;
    src = W2; dst = W2T; K = FF; N = EMBED; nbt = t % 24; kbt = t / 24;
  }
  const int tx = tid & 31, ty = tid >> 5;     // (32,8)
  int nb = nbt * 32, kb = kbt * 32;
  for (int i = ty; i < 32; i += 8)
    tile[i][tx] = src[(size_t)(kb + i) * N + nb + tx];
  __syncthreads();
  for (int i = ty; i < 32; i += 8)
    dst[(size_t)(nb + i) * K + kb + tx] = (bf16)tile[tx][i];
}

enum { MODE_QKV = 0, MODE_EXP = 1, MODE_F32 = 2, MODE_GELU = 3, MODE_SPLIT = 4 };

// ============================ 128^2 kernel — round-0 proven, byte-identical ===
// C[M][N] = A[M][K] . BT[N][K]^T, bf16 in. BK=64, 32 KB LDS, single-buffered,
// 2-barrier K-loop, ~3 blocks/CU. Used for EXP / PV / FFN2 (grids that
// underfill at 256^2). CLOSED EXPERIMENTS: R3/R5/R8 (see journal).
template <int MODE>
__global__ void gemm_nt(const bf16* __restrict__ A, const bf16* __restrict__ B,
                        void* __restrict__ C, const float* __restrict__ bias, float alpha,
                        int M, int N, int K, int lda, int ldb, long sA, long sB, long sC,
                        void* __restrict__ C2, void* __restrict__ C3,
                        const float* __restrict__ bias2, const float* __restrict__ bias3) {
  __shared__ bf16 sAl[128 * 64];   // 16 KB
  __shared__ bf16 sBl[128 * 64];
  const int tid  = threadIdx.x;
  const int lane = tid & 63;
  const int wave = tid >> 6;
  const int wm   = (wave >> 1) * 64;
  const int wn   = (wave & 1) * 64;
  const int quad = lane >> 4;
  const int l15  = lane & 15;
  const int l7   = lane & 7;

  int bx = blockIdx.x, by = blockIdx.y;
  if (gridDim.z == 1 && (gridDim.y & 7) == 0) {
    const int gx = gridDim.x, gy = gridDim.y;
    const int b  = by * gx + bx;
    const int xcd = b & 7, s = b >> 3;
    bx = s % gx;
    by = xcd * (gy >> 3) + s / gx;
  }

  int split = 0, batch = blockIdx.z;
  if constexpr (MODE == MODE_SPLIT) { split = blockIdx.z & 1; batch = blockIdx.z >> 1; }

  const bf16* Ab = A + (size_t)batch * sA + (size_t)split * K + (size_t)by * 128 * lda;
  const bf16* Bb = B + (size_t)batch * sB + (size_t)split * K + (size_t)bx * 128 * ldb;

  f32x4 acc[4][4] = {};

  for (int k0 = 0; k0 < K; k0 += 64) {
#pragma unroll
    for (int c = 0; c < 4; ++c) {
      int f   = c * 256 + tid;                 // 0..1023 chunk of 16B
      int row = f >> 3;                        // 0..127
      int col = ((f & 7) ^ (row & 7)) * 8;     // swizzled bf16 col within 64-wide stage
      __builtin_amdgcn_global_load_lds(
          (__attribute__((address_space(1))) void*)(Ab + (size_t)row * lda + k0 + col),
          (__attribute__((address_space(3))) void*)(sAl + (size_t)(c * 256 + wave * 64) * 8),
          16, 0, 0);
      __builtin_amdgcn_global_load_lds(
          (__attribute__((address_space(1))) void*)(Bb + (size_t)row * ldb + k0 + col),
          (__attribute__((address_space(3))) void*)(sBl + (size_t)(c * 256 + wave * 64) * 8),
          16, 0, 0);
    }
    __syncthreads();
#pragma unroll
    for (int kk = 0; kk < 2; ++kk) {
      const int ga = (((kk << 2) | quad) ^ l7) * 8;   // swizzled granule for this lane
      bf16x8 af[4], bfr[4];
#pragma unroll
      for (int t = 0; t < 4; ++t) {
        af[t]  = *(const bf16x8*)&sAl[(wm + t * 16 + l15) * 64 + ga];
        bfr[t] = *(const bf16x8*)&sBl[(wn + t * 16 + l15) * 64 + ga];
      }
#pragma unroll
      for (int mt = 0; mt < 4; ++mt)
#pragma unroll
        for (int nt = 0; nt < 4; ++nt)
          acc[mt][nt] = __builtin_amdgcn_mfma_f32_16x16x32_bf16(af[mt], bfr[nt], acc[mt][nt], 0, 0, 0);
    }
    __syncthreads();
  }

  // epilogue: D row = quad*4 + r (+16*mt), col = l15 (+16*nt)   [m89-verified]
  const size_t mbase = (size_t)by * 128 + wm + quad * 4;

  if constexpr (MODE == MODE_QKV) {
    const int region = (bx * 128) / 768;     // 0=Q 1=K 2=V
    const int nloc0  = bx * 128 - region * 768 + wn + l15;
    const float* bs  = (region == 0) ? bias : (region == 1 ? bias2 : bias3);
    const float  a   = (region == 0) ? alpha : 1.0f;
    if (region == 2) {
#pragma unroll
      for (int mt = 0; mt < 4; ++mt)
#pragma unroll
        for (int nt = 0; nt < 4; ++nt) {
          size_t m0 = mbase + mt * 16;
          int nl = nloc0 + nt * 16;
          bf16x4 pk;
#pragma unroll
          for (int r = 0; r < 4; ++r) pk[r] = (bf16)(acc[mt][nt][r] + bs[nl]);
          size_t b = m0 >> 10, s = m0 & 1023;
          *(bf16x4*)&((bf16*)C3)[b * ((size_t)EMBED * SEQ) + (size_t)nl * SEQ + s] = pk;
        }
    } else {
#pragma unroll
      for (int mt = 0; mt < 4; ++mt)
#pragma unroll
        for (int r = 0; r < 4; ++r) {
          size_t m = mbase + mt * 16 + r;
#pragma unroll
          for (int nt = 0; nt < 4; ++nt) {
            int nl  = nloc0 + nt * 16;
            float v = (acc[mt][nt][r] + bs[nl]) * a;
            if (region == 0) ((bf16*)C )[m * EMBED + nl] = (bf16)v;
            else             ((bf16*)C2)[m * EMBED + nl] = (bf16)v;
          }
        }
    }
  } else if constexpr (MODE == MODE_EXP) {
    float* rowsum = (float*)C2;
#pragma unroll
    for (int mt = 0; mt < 4; ++mt)
#pragma unroll
      for (int r = 0; r < 4; ++r) {
        size_t m = mbase + mt * 16 + r;
        float part = 0.f;
#pragma unroll
        for (int nt = 0; nt < 4; ++nt) {
          size_t n = (size_t)bx * 128 + wn + l15 + nt * 16;
          float e = __expf(acc[mt][nt][r]);
          part += e;
          ((bf16*)C)[(size_t)batch * sC + m * N + n] = (bf16)e;
        }
        part += __shfl_xor(part, 1);
        part += __shfl_xor(part, 2);
        part += __shfl_xor(part, 4);
        part += __shfl_xor(part, 8);
        if (l15 == 0) atomicAdd(&rowsum[(size_t)batch * SEQ + m], part);
      }
  } else if constexpr (MODE == MODE_SPLIT) {
    bf16* Cp = (bf16*)(split ? C2 : C) + (size_t)batch * sC;
#pragma unroll
    for (int mt = 0; mt < 4; ++mt)
#pragma unroll
      for (int r = 0; r < 4; ++r) {
        size_t m = mbase + mt * 16 + r;
#pragma unroll
        for (int nt = 0; nt < 4; ++nt) {
          size_t n = (size_t)bx * 128 + wn + l15 + nt * 16;
          Cp[m * N + n] = (bf16)acc[mt][nt][r];
        }
      }
  } else {
    const size_t nbase = (size_t)bx * 128 + wn + l15;
#pragma unroll
    for (int mt = 0; mt < 4; ++mt)
#pragma unroll
      for (int r = 0; r < 4; ++r) {
        size_t m = mbase + mt * 16 + r;
#pragma unroll
        for (int nt = 0; nt < 4; ++nt) {
          size_t n = nbase + nt * 16;
          float v = acc[mt][nt][r];
          if (bias) v += bias[n];
          v *= alpha;
          if constexpr (MODE == MODE_GELU) {
            float y = 1.5957691216f * (v + 0.044715f * v * v * v);
            float g = v * __builtin_amdgcn_rcpf(1.0f + __expf(-y));
            ((bf16*)C)[m * (size_t)N + n] = (bf16)g;
          } else {
            ((float*)C)[(size_t)batch * sC + m * (size_t)N + n] = v;
          }
        }
      }
  }
}

// ============================ 256^2 kernel — R10: interleaved dbuf schedule ===
// 256x256 tile, BK=64, 8 waves (2Mx4N, 128x64/wave), 128 KiB LDS dbuf.
// Per K-tile: vmcnt(8); B1; [bfr+af01 reads; 4x {read af-quadrant q+1 || 16
// MFMA quadrant q}]; lgkmcnt(0); B2; stage(kt+2, freed buf).
// R9 POST-MORTEM (closed): B2-before-MFMA serialized the 2300-cyc LDS phase
// and 2064-cyc MFMA phase at 1 block/CU -> 13% MfmaUtil. This version keeps
// the buffer-free barrier AFTER the consuming MFMAs and interleaves reads
// with MFMAs inside the phase (m201-style).
template <int MODE>
__launch_bounds__(512, 2)
__global__ void gemm_nt256(const bf16* __restrict__ A, const bf16* __restrict__ B,
                           void* __restrict__ C, const float* __restrict__ bias, float alpha,
                           int M, int N, int K, int lda, int ldb, long sA, long sB, long sC,
                           void* __restrict__ C2, void* __restrict__ C3,
                           const float* __restrict__ bias2, const float* __restrict__ bias3) {
  __shared__ bf16 sAl[2][256 * 64];   // 64 KB
  __shared__ bf16 sBl[2][256 * 64];   // 64 KB
  const int tid  = threadIdx.x;
  const int lane = tid & 63;
  const int wave = tid >> 6;          // 0..7
  const int wm   = (wave >> 2) * 128; // 2 wave-rows of 128
  const int wn   = (wave & 3) * 64;   // 4 wave-cols of 64
  const int quad = lane >> 4;
  const int l15  = lane & 15;
  const int l7   = lane & 7;

  int bx = blockIdx.x, by = blockIdx.y;
  if (gridDim.z == 1 && (gridDim.y & 7) == 0) {
    const int gx = gridDim.x, gy = gridDim.y;
    const int b  = by * gx + bx;
    const int xcd = b & 7, s = b >> 3;
    bx = s % gx;
    by = xcd * (gy >> 3) + s / gx;
  }

  int split = 0, batch = blockIdx.z;
  if constexpr (MODE == MODE_SPLIT) { split = blockIdx.z & 1; batch = blockIdx.z >> 1; }

  const bf16* Ab = A + (size_t)batch * sA + (size_t)split * K + (size_t)by * 256 * lda;
  const bf16* Bb = B + (size_t)batch * sB + (size_t)split * K + (size_t)bx * 256 * ldb;

  const int NT = K >> 6;   // K-tiles of 64; all call sites have NT >= 12

  // stage K-tile kt into buffer bb: A 256x64 + B 256x64 bf16, 8 x gl_lds(16B)
  // per thread. Global src pre-swizzled (granule ^ row&7), linear LDS dest.
  auto stage = [&](int kt, int bb) {
    const int k0 = kt << 6;
#pragma unroll
    for (int i = 0; i < 4; ++i) {
      const int f   = i * 512 + tid;           // 16B chunk 0..2047
      const int row = f >> 3;                  // 0..255
      const int col = ((f & 7) ^ (row & 7)) << 3;
      __builtin_amdgcn_global_load_lds(
          (__attribute__((address_space(1))) void*)(Ab + (size_t)row * lda + k0 + col),
          (__attribute__((address_space(3))) void*)(&sAl[bb][0] + (size_t)(i * 512 + wave * 64) * 8),
          16, 0, 0);
      __builtin_amdgcn_global_load_lds(
          (__attribute__((address_space(1))) void*)(Bb + (size_t)row * ldb + k0 + col),
          (__attribute__((address_space(3))) void*)(&sBl[bb][0] + (size_t)(i * 512 + wave * 64) * 8),
          16, 0, 0);
    }
  };

  stage(0, 0);
  stage(1, 1);

  f32x4 acc[8][4] = {};

  for (int kt = 0; kt < NT; ++kt) {
    const int b = kt & 1;
    // counted wait: tile kt's 8 loads are the oldest; kt+1's 8 stay in flight.
    if (kt + 1 < NT) asm volatile("s_waitcnt vmcnt(8)");
    else             asm volatile("s_waitcnt vmcnt(0)");
    __builtin_amdgcn_s_barrier();              // B1: buf b stores visible to all
    __builtin_amdgcn_sched_barrier(0);         // no ds_read may hoist above B1

    const bf16* __restrict__ sA_ = &sAl[b][0];
    const bf16* __restrict__ sB_ = &sBl[b][0];
    bf16x8 af[8][2], bfr[4][2];
    // prologue reads: all B frags (8) + A quadrant 0 (4)
#pragma unroll
    for (int nt = 0; nt < 4; ++nt) {
      const int row = wn + nt * 16 + l15;
#pragma unroll
      for (int kk = 0; kk < 2; ++kk)
        bfr[nt][kk] = *(const bf16x8*)&sB_[row * 64 + ((((kk << 2) | quad) ^ l7) << 3)];
    }
#pragma unroll
    for (int mt = 0; mt < 2; ++mt) {
      const int row = wm + mt * 16 + l15;
#pragma unroll
      for (int kk = 0; kk < 2; ++kk)
        af[mt][kk] = *(const bf16x8*)&sA_[row * 64 + ((((kk << 2) | quad) ^ l7) << 3)];
    }
    // 4 quadrants: read af for q+1 while MFMA'ing quadrant q
#pragma unroll
    for (int q = 0; q < 4; ++q) {
      if (q < 3) {
#pragma unroll
        for (int m2 = 0; m2 < 2; ++m2) {
          const int mt  = 2 * q + 2 + m2;
          const int row = wm + mt * 16 + l15;
#pragma unroll
          for (int kk = 0; kk < 2; ++kk)
            af[mt][kk] = *(const bf16x8*)&sA_[row * 64 + ((((kk << 2) | quad) ^ l7) << 3)];
        }
      }
      __builtin_amdgcn_s_setprio(1);
#pragma unroll
      for (int m2 = 0; m2 < 2; ++m2) {
        const int mt = 2 * q + m2;
#pragma unroll
        for (int nt = 0; nt < 4; ++nt)
#pragma unroll
          for (int kk = 0; kk < 2; ++kk)
            acc[mt][nt] = __builtin_amdgcn_mfma_f32_16x16x32_bf16(af[mt][kk], bfr[nt][kk], acc[mt][nt], 0, 0, 0);
      }
      __builtin_amdgcn_s_setprio(0);
    }
    __builtin_amdgcn_sched_barrier(0);
    asm volatile("s_waitcnt lgkmcnt(0)");      // all my reads of buf b done
    __builtin_amdgcn_sched_barrier(0);
    __builtin_amdgcn_s_barrier();              // B2: everyone done reading buf b
    __builtin_amdgcn_sched_barrier(0);
    if (kt + 2 < NT) stage(kt + 2, b);         // refill just-freed buffer
  }

  // epilogue: D row = quad*4 + r (+16*mt), col = l15 (+16*nt)   [m89-verified]
  const size_t mbase = (size_t)by * 256 + wm + quad * 4;

  if constexpr (MODE == MODE_QKV) {
    const int region = (bx * 256) / 768;     // 0=Q 1=K 2=V (768 % 256 == 0)
    const int nloc0  = bx * 256 - region * 768 + wn + l15;
    const float* bs  = (region == 0) ? bias : (region == 1 ? bias2 : bias3);
    const float  a   = (region == 0) ? alpha : 1.0f;
    if (region == 2) {
#pragma unroll
      for (int mt = 0; mt < 8; ++mt)
#pragma unroll
        for (int nt = 0; nt < 4; ++nt) {
          size_t m0 = mbase + mt * 16;          // %4 == 0, no batch crossing
          int nl = nloc0 + nt * 16;
          bf16x4 pk;
#pragma unroll
          for (int r = 0; r < 4; ++r) pk[r] = (bf16)(acc[mt][nt][r] + bs[nl]);
          size_t bb = m0 >> 10, s = m0 & 1023;
          *(bf16x4*)&((bf16*)C3)[bb * ((size_t)EMBED * SEQ) + (size_t)nl * SEQ + s] = pk;
        }
    } else {
#pragma unroll
      for (int mt = 0; mt < 8; ++mt)
#pragma unroll
        for (int r = 0; r < 4; ++r) {
          size_t m = mbase + mt * 16 + r;
#pragma unroll
          for (int nt = 0; nt < 4; ++nt) {
            int nl  = nloc0 + nt * 16;
            float v = (acc[mt][nt][r] + bs[nl]) * a;
            if (region == 0) ((bf16*)C )[m * EMBED + nl] = (bf16)v;
            else             ((bf16*)C2)[m * EMBED + nl] = (bf16)v;
          }
        }
    }
  } else {
    const size_t nbase = (size_t)bx * 256 + wn + l15;
#pragma unroll
    for (int mt = 0; mt < 8; ++mt)
#pragma unroll
      for (int r = 0; r < 4; ++r) {
        size_t m = mbase + mt * 16 + r;
#pragma unroll
        for (int nt = 0; nt < 4; ++nt) {
          size_t n = nbase + nt * 16;
          float v = acc[mt][nt][r];
          if (bias) v += bias[n];
          v *= alpha;
          if constexpr (MODE == MODE_GELU) {
            float y = 1.5957691216f * (v + 0.044715f * v * v * v);
            float g = v * __builtin_amdgcn_rcpf(1.0f + __expf(-y));
            ((bf16*)C)[m * (size_t)N + n] = (bf16)g;
          } else {
            ((float*)C)[(size_t)batch * sC + m * (size_t)N + n] = v;
          }
        }
      }
  }
}

// ---- per-wave row LN: out = xres + LN((y0+y1)*inv_rs + yb)*g + beta
template <int HAS_RS, int HAS_BIAS, int OUT_F32>
__global__ void add_ln_kernel(const bf16* __restrict__ xres, const bf16* __restrict__ y0,
                              const bf16* __restrict__ y1, const float* __restrict__ yb,
                              const float* __restrict__ rowsum,
                              const float* __restrict__ g, const float* __restrict__ beta,
                              float* __restrict__ out, bf16* __restrict__ outb) {
  const int lane = threadIdx.x & 63;
  const int wv   = threadIdx.x >> 6;
  const size_t row = (size_t)blockIdx.x * 4 + wv;
  const float inv_rs = HAS_RS ? (1.0f / rowsum[row]) : 1.0f;
  const bf16x4* y0p = (const bf16x4*)(y0 + row * EMBED);
  const bf16x4* y1p = (const bf16x4*)(y1 + row * EMBED);
  float v[12];
  float s = 0.f, q = 0.f;
#pragma unroll
  for (int c = 0; c < 3; ++c) {
    int ch = c * 64 + lane;          // bf16x4 chunk 0..191
    bf16x4 a = y0p[ch], b = y1p[ch];
#pragma unroll
    for (int j = 0; j < 4; ++j) {
      float t = ((float)a[j] + (float)b[j]) * inv_rs;
      if (HAS_BIAS) t += yb[ch * 4 + j];
      v[c * 4 + j] = t; s += t; q += t * t;
    }
  }
#pragma unroll
  for (int o = 1; o < 64; o <<= 1) { s += __shfl_xor(s, o); q += __shfl_xor(q, o); }
  const float mu  = s * (1.0f / EMBED);
  const float var = q * (1.0f / EMBED) - mu * mu;
  const float inv = rsqrtf(var + 1e-5f);
  const bf16x4* xp = (const bf16x4*)(xres + row * EMBED);
#pragma unroll
  for (int c = 0; c < 3; ++c) {
    int ch = c * 64 + lane;
    bf16x4 xv = xp[ch];
    float4 o4; bf16x4 ob;
#pragma unroll
    for (int j = 0; j < 4; ++j) {
      int col = ch * 4 + j;
      float o = (v[c * 4 + j] - mu) * inv * g[col] + beta[col] + (float)xv[j];
      ((float*)&o4)[j] = o;
      ob[j] = (bf16)o;
    }
    if (OUT_F32) ((float4*)(out + row * EMBED))[ch] = o4;
    else         ((bf16x4*)(outb + row * EMBED))[ch] = ob;
  }
}

// ---------------------------------------------------------------- launcher
extern "C" void kernel_launch(void* const* d_in, const int* in_sizes, int n_in,
                              void* d_out, int out_size, void* d_ws, size_t ws_size,
                              hipStream_t stream) {
  const float* x   = (const float*)d_in[0];
  const float* Wq  = (const float*)d_in[1];
  const float* bq  = (const float*)d_in[2];
  const float* Wk  = (const float*)d_in[3];
  const float* bk  = (const float*)d_in[4];
  const float* Wv  = (const float*)d_in[5];
  const float* bv  = (const float*)d_in[6];
  const float* W1  = (const float*)d_in[7];
  const float* b1  = (const float*)d_in[8];
  const float* W2  = (const float*)d_in[9];
  const float* b2  = (const float*)d_in[10];
  const float* g1  = (const float*)d_in[11];
  const float* be1 = (const float*)d_in[12];
  const float* g2  = (const float*)d_in[13];
  const float* be2 = (const float*)d_in[14];

  // workspace layout (bytes, peak 159,776,768 — proven)
  char* ws = (char*)d_ws;
  bf16*  xb    = (bf16*)(ws + 0);            // 12,582,912
  bf16*  WqkvT = (bf16*)(ws + 12582912);     //  3,538,944  [2304][768]
  bf16*  W1T   = (bf16*)(ws + 16121856);     //  4,718,592
  bf16*  W2T   = (bf16*)(ws + 20840448);     //  4,718,592
  bf16*  x1b   = (bf16*)(ws + 25559040);     // 12,582,912  (x1 residual, bf16)
  bf16*  Qs    = (bf16*)(ws + 38141952);     // 12,582,912
  bf16*  Kb    = (bf16*)(ws + 50724864);     // 12,582,912
  bf16*  VT    = (bf16*)(ws + 63307776);     // 12,582,912
  float* rowsum= (float*)(ws + 75890688);    //     32,768
  bf16*  P     = (bf16*)(ws + 92667904);     // 16,777,216  (unnormalized exp scores)
  bf16*  att0  = (bf16*)(ws + 109445120);    // 12,582,912  PV partial 0 (bf16)
  bf16*  att1  = (bf16*)(ws + 134610944);    // 12,582,912  PV partial 1 (bf16)
  bf16*  H     = (bf16*)(ws + 38141952);     // 50,331,648 over Qs..P-area (dead by FFN1)
  bf16*  F0    = (bf16*)(ws + 109445120);    // over att0 (dead by FFN2)
  bf16*  F1    = (bf16*)(ws + 134610944);    // over att1 (dead by FFN2)

  const float scale = 0.036084391824351615f;  // 768^-0.5

  // fused prep: all 5 transposes + x->bf16 + rowsum zero (one launch)
  prep_kernel<<<12480, 256, 0, stream>>>(Wq, Wk, Wv, W1, W2, WqkvT, W1T, W2T, x, xb, rowsum);

  // fused QKV projection (scale folded into Q region) — 256^2, 288 blocks
  gemm_nt256<MODE_QKV><<<dim3(2304 / 256, ROWS / 256, 1), 512, 0, stream>>>(
      xb, WqkvT, Qs, bq, scale, ROWS, 2304, EMBED, EMBED, EMBED, 0, 0, 0, Kb, VT, bk, bv);

  // P~ = exp(Qs . K^T), rowsums atomically — 128^2 (grid fill: 512 blocks)
  gemm_nt<MODE_EXP><<<dim3(SEQ / 128, SEQ / 128, BATCH), 256, 0, stream>>>(
      Qs, Kb, P, nullptr, 1.f, SEQ, SEQ, EMBED, EMBED, EMBED,
      (long)SEQ * EMBED, (long)SEQ * EMBED, (long)SEQ * SEQ,
      rowsum, nullptr, nullptr, nullptr);

  // att~ = P~ . V  (batched, split-K=2, bf16 partials) — 128^2 (768 blocks)
  gemm_nt<MODE_SPLIT><<<dim3(EMBED / 128, SEQ / 128, BATCH * 2), 256, 0, stream>>>(
      P, VT, att0, nullptr, 1.f, SEQ, EMBED, SEQ / 2, SEQ, SEQ,
      (long)SEQ * SEQ, (long)EMBED * SEQ, (long)SEQ * EMBED, att1, nullptr, nullptr, nullptr);

  // x1 = xb + LN((att0+att1)/rowsum)  -> bf16
  add_ln_kernel<1, 0, 0><<<ROWS / 4, 256, 0, stream>>>(
      xb, att0, att1, nullptr, rowsum, g1, be1, nullptr, x1b);

  // FFN1 (GELU, bf16 out) — 256^2, 384 blocks
  gemm_nt256<MODE_GELU><<<dim3(FF / 256, ROWS / 256, 1), 512, 0, stream>>>(
      x1b, W1T, H, b1, 1.f, ROWS, FF, EMBED, EMBED, EMBED, 0, 0, 0,
      nullptr, nullptr, nullptr, nullptr);

  // FFN2 (split-K=2, bias deferred to LN stage, bf16 partials) — 128^2 (768 blocks)
  gemm_nt<MODE_SPLIT><<<dim3(EMBED / 128, ROWS / 128, 2), 256, 0, stream>>>(
      H, W2T, F0, nullptr, 1.f, ROWS, EMBED, FF / 2, FF, FF, 0, 0, 0,
      F1, nullptr, nullptr, nullptr);

  // out = x1b + LN(F0+F1+b2)  -> fp32
  add_ln_kernel<0, 1, 1><<<ROWS / 4, 256, 0, stream>>>(
      x1b, F0, F1, b2, nullptr, g2, be2, (float*)d_out, nullptr);
}

// Round 3
// 389.192 us; speedup vs baseline: 1.0153x; 1.0153x over previous
//
#include <hip/hip_runtime.h>
#include <cstdint>
#include <cstddef>

typedef __bf16 bf16;
typedef __bf16 bf16x8 __attribute__((ext_vector_type(8)));
typedef __bf16 bf16x4 __attribute__((ext_vector_type(4)));
typedef float  f32x4  __attribute__((ext_vector_type(4)));

#define EMBED 768
#define FF    3072
#define SEQ   1024
#define BATCH 8
#define ROWS  (BATCH * SEQ)   // 8192

// ---------------- fused prep: 5 weight transposes (fp32 [K][N] -> bf16 [N][K]),
// x -> bf16, rowsum zero.
__global__ void prep_kernel(const float* __restrict__ Wq, const float* __restrict__ Wk,
                            const float* __restrict__ Wv, const float* __restrict__ W1,
                            const float* __restrict__ W2, bf16* __restrict__ WqkvT,
                            bf16* __restrict__ W1T, bf16* __restrict__ W2T,
                            const float* __restrict__ x, bf16* __restrict__ xb,
                            float* __restrict__ rowsum) {
  const int id = blockIdx.x;
  const int tid = threadIdx.x;
  if (id >= 6336) {
    int i = (id - 6336) * 256 + tid;          // float4 chunk of x
    float4 v = ((const float4*)x)[i];
    bf16x4 o;
    o.x = (bf16)v.x; o.y = (bf16)v.y; o.z = (bf16)v.z; o.w = (bf16)v.w;
    ((bf16x4*)xb)[i] = o;
    if (i < ROWS) rowsum[i] = 0.f;
    return;
  }
  __shared__ float tile[32][33];
  const float* src; bf16* dst; int K, N, nbt, kbt;
  if (id < 1728) {
    int w = id / 576, t = id % 576;
    src = (w == 0) ? Wq : (w == 1 ? Wk : Wv);
    dst = WqkvT + (size_t)w * EMBED * EMBED;
    K = EMBED; N = EMBED; nbt = t % 24; kbt = t / 24;
  } else if (id < 4032) {
    int t = id - 1728;
    src = W1; dst = W1T; K = EMBED; N = FF; nbt = t % 96; kbt = t / 96;
  } else {
    int t = id - 4032;
    src = W2; dst = W2T; K = FF; N = EMBED; nbt = t % 24; kbt = t / 24;
  }
  const int tx = tid & 31, ty = tid >> 5;     // (32,8)
  int nb = nbt * 32, kb = kbt * 32;
  for (int i = ty; i < 32; i += 8)
    tile[i][tx] = src[(size_t)(kb + i) * N + nb + tx];
  __syncthreads();
  for (int i = ty; i < 32; i += 8)
    dst[(size_t)(nb + i) * K + kb + tx] = (bf16)tile[tx][i];
}

enum { MODE_QKV = 0, MODE_EXP = 1, MODE_F32 = 2, MODE_GELU = 3, MODE_SPLIT = 4 };

// ---------------------------------------------------------------- MFMA NT GEMM
// C[M][N] = A[M][K] . BT[N][K]^T, bf16 in. 128^2 tile, BK=64, 4 waves.
// R11: T3 "minimum 2-phase" double-buffer (m230/m248/m228d-verified recipe):
//   prologue STAGE(buf0); sync
//   per tile: STAGE(buf[t+1]) FIRST; ds_read+MFMA on buf[t]; ONE syncthreads
// The trailing __syncthreads' vmcnt(0) drains loads issued a full compute
// phase (~2500 cyc) earlier -> cheap; its lgkmcnt(0) proves all reads of
// buf[t] done before iteration t+1 overwrites it. 64 KB LDS -> 2 blocks/CU.
// CLOSED (do not revisit): R3 dbuf+2-barrier (occupancy loss, no gain);
// R5 BK=32 swizzle; R8 1-barrier dbuf at BK=32 (shadow too short, drain
// serialized); R9/R10 256^2 1-block/CU counted-vmcnt ports (10k cyc/tile,
// no inter-block overlap to hide stalls).
template <int MODE>
__global__ void gemm_nt(const bf16* __restrict__ A, const bf16* __restrict__ B,
                        void* __restrict__ C, const float* __restrict__ bias, float alpha,
                        int M, int N, int K, int lda, int ldb, long sA, long sB, long sC,
                        void* __restrict__ C2, void* __restrict__ C3,
                        const float* __restrict__ bias2, const float* __restrict__ bias3) {
  __shared__ bf16 sAl[2][128 * 64];   // 32 KB
  __shared__ bf16 sBl[2][128 * 64];   // 32 KB
  const int tid  = threadIdx.x;
  const int lane = tid & 63;
  const int wave = tid >> 6;
  const int wm   = (wave >> 1) * 64;
  const int wn   = (wave & 1) * 64;
  const int quad = lane >> 4;
  const int l15  = lane & 15;
  const int l7   = lane & 7;

  int bx = blockIdx.x, by = blockIdx.y;
  if (gridDim.z == 1 && (gridDim.y & 7) == 0) {
    const int gx = gridDim.x, gy = gridDim.y;
    const int b  = by * gx + bx;
    const int xcd = b & 7, s = b >> 3;
    bx = s % gx;
    by = xcd * (gy >> 3) + s / gx;
  }

  int split = 0, batch = blockIdx.z;
  if constexpr (MODE == MODE_SPLIT) { split = blockIdx.z & 1; batch = blockIdx.z >> 1; }

  const bf16* Ab = A + (size_t)batch * sA + (size_t)split * K + (size_t)by * 128 * lda;
  const bf16* Bb = B + (size_t)batch * sB + (size_t)split * K + (size_t)bx * 128 * ldb;

  const int NT = K >> 6;   // K-tiles of 64; all call sites have NT >= 8

  // stage K-tile kt into buffer bb. Global src pre-swizzled (granule ^ row&7),
  // linear LDS dest (wave-uniform base + lane*16B) — proven conflict-free pair.
  auto stage = [&](int kt, int bb) {
    const int k0 = kt << 6;
#pragma unroll
    for (int c = 0; c < 4; ++c) {
      int f   = c * 256 + tid;                 // 0..1023 chunk of 16B
      int row = f >> 3;                        // 0..127
      int col = ((f & 7) ^ (row & 7)) * 8;     // swizzled bf16 col within 64-wide stage
      __builtin_amdgcn_global_load_lds(
          (__attribute__((address_space(1))) void*)(Ab + (size_t)row * lda + k0 + col),
          (__attribute__((address_space(3))) void*)(&sAl[bb][0] + (size_t)(c * 256 + wave * 64) * 8),
          16, 0, 0);
      __builtin_amdgcn_global_load_lds(
          (__attribute__((address_space(1))) void*)(Bb + (size_t)row * ldb + k0 + col),
          (__attribute__((address_space(3))) void*)(&sBl[bb][0] + (size_t)(c * 256 + wave * 64) * 8),
          16, 0, 0);
    }
  };

  stage(0, 0);
  __syncthreads();                             // buf0 ready (vmcnt(0)+barrier)

  f32x4 acc[4][4] = {};

  for (int t = 0; t < NT; ++t) {
    const int cur = t & 1;
    if (t + 1 < NT) stage(t + 1, cur ^ 1);     // issue next-tile loads FIRST
    __builtin_amdgcn_sched_barrier(0);         // keep gl_lds issue ahead of reads

    const bf16* __restrict__ sA_ = &sAl[cur][0];
    const bf16* __restrict__ sB_ = &sBl[cur][0];
#pragma unroll
    for (int kk = 0; kk < 2; ++kk) {
      const int ga = (((kk << 2) | quad) ^ l7) * 8;   // swizzled granule for this lane
      bf16x8 af[4], bfr[4];
#pragma unroll
      for (int tt = 0; tt < 4; ++tt) {
        af[tt]  = *(const bf16x8*)&sA_[(wm + tt * 16 + l15) * 64 + ga];
        bfr[tt] = *(const bf16x8*)&sB_[(wn + tt * 16 + l15) * 64 + ga];
      }
#pragma unroll
      for (int mt = 0; mt < 4; ++mt)
#pragma unroll
        for (int nt = 0; nt < 4; ++nt)
          acc[mt][nt] = __builtin_amdgcn_mfma_f32_16x16x32_bf16(af[mt], bfr[nt], acc[mt][nt], 0, 0, 0);
    }
    if (t + 1 < NT) __syncthreads();           // vmcnt(0): buf[t+1] staged;
                                               // lgkmcnt(0): my reads of buf[t] done
  }

  // epilogue: D row = quad*4 + r (+16*mt), col = l15 (+16*nt)   [m89-verified]
  const size_t mbase = (size_t)by * 128 + wm + quad * 4;

  if constexpr (MODE == MODE_QKV) {
    const int region = (bx * 128) / 768;     // 0=Q 1=K 2=V
    const int nloc0  = bx * 128 - region * 768 + wn + l15;
    const float* bs  = (region == 0) ? bias : (region == 1 ? bias2 : bias3);
    const float  a   = (region == 0) ? alpha : 1.0f;
    if (region == 2) {
#pragma unroll
      for (int mt = 0; mt < 4; ++mt)
#pragma unroll
        for (int nt = 0; nt < 4; ++nt) {
          size_t m0 = mbase + mt * 16;
          int nl = nloc0 + nt * 16;
          bf16x4 pk;
#pragma unroll
          for (int r = 0; r < 4; ++r) pk[r] = (bf16)(acc[mt][nt][r] + bs[nl]);
          size_t b = m0 >> 10, s = m0 & 1023;
          *(bf16x4*)&((bf16*)C3)[b * ((size_t)EMBED * SEQ) + (size_t)nl * SEQ + s] = pk;
        }
    } else {
#pragma unroll
      for (int mt = 0; mt < 4; ++mt)
#pragma unroll
        for (int r = 0; r < 4; ++r) {
          size_t m = mbase + mt * 16 + r;
#pragma unroll
          for (int nt = 0; nt < 4; ++nt) {
            int nl  = nloc0 + nt * 16;
            float v = (acc[mt][nt][r] + bs[nl]) * a;
            if (region == 0) ((bf16*)C )[m * EMBED + nl] = (bf16)v;
            else             ((bf16*)C2)[m * EMBED + nl] = (bf16)v;
          }
        }
    }
  } else if constexpr (MODE == MODE_EXP) {
    float* rowsum = (float*)C2;
#pragma unroll
    for (int mt = 0; mt < 4; ++mt)
#pragma unroll
      for (int r = 0; r < 4; ++r) {
        size_t m = mbase + mt * 16 + r;
        float part = 0.f;
#pragma unroll
        for (int nt = 0; nt < 4; ++nt) {
          size_t n = (size_t)bx * 128 + wn + l15 + nt * 16;
          float e = __expf(acc[mt][nt][r]);
          part += e;
          ((bf16*)C)[(size_t)batch * sC + m * N + n] = (bf16)e;
        }
        part += __shfl_xor(part, 1);
        part += __shfl_xor(part, 2);
        part += __shfl_xor(part, 4);
        part += __shfl_xor(part, 8);
        if (l15 == 0) atomicAdd(&rowsum[(size_t)batch * SEQ + m], part);
      }
  } else if constexpr (MODE == MODE_SPLIT) {
    bf16* Cp = (bf16*)(split ? C2 : C) + (size_t)batch * sC;
#pragma unroll
    for (int mt = 0; mt < 4; ++mt)
#pragma unroll
      for (int r = 0; r < 4; ++r) {
        size_t m = mbase + mt * 16 + r;
#pragma unroll
        for (int nt = 0; nt < 4; ++nt) {
          size_t n = (size_t)bx * 128 + wn + l15 + nt * 16;
          Cp[m * N + n] = (bf16)acc[mt][nt][r];
        }
      }
  } else {
    const size_t nbase = (size_t)bx * 128 + wn + l15;
#pragma unroll
    for (int mt = 0; mt < 4; ++mt)
#pragma unroll
      for (int r = 0; r < 4; ++r) {
        size_t m = mbase + mt * 16 + r;
#pragma unroll
        for (int nt = 0; nt < 4; ++nt) {
          size_t n = nbase + nt * 16;
          float v = acc[mt][nt][r];
          if (bias) v += bias[n];
          v *= alpha;
          if constexpr (MODE == MODE_GELU) {
            float y = 1.5957691216f * (v + 0.044715f * v * v * v);
            float g = v * __builtin_amdgcn_rcpf(1.0f + __expf(-y));
            ((bf16*)C)[m * (size_t)N + n] = (bf16)g;
          } else {
            ((float*)C)[(size_t)batch * sC + m * (size_t)N + n] = v;
          }
        }
      }
  }
}

// ---- per-wave row LN: out = xres + LN((y0+y1)*inv_rs + yb)*g + beta
template <int HAS_RS, int HAS_BIAS, int OUT_F32>
__global__ void add_ln_kernel(const bf16* __restrict__ xres, const bf16* __restrict__ y0,
                              const bf16* __restrict__ y1, const float* __restrict__ yb,
                              const float* __restrict__ rowsum,
                              const float* __restrict__ g, const float* __restrict__ beta,
                              float* __restrict__ out, bf16* __restrict__ outb) {
  const int lane = threadIdx.x & 63;
  const int wv   = threadIdx.x >> 6;
  const size_t row = (size_t)blockIdx.x * 4 + wv;
  const float inv_rs = HAS_RS ? (1.0f / rowsum[row]) : 1.0f;
  const bf16x4* y0p = (const bf16x4*)(y0 + row * EMBED);
  const bf16x4* y1p = (const bf16x4*)(y1 + row * EMBED);
  float v[12];
  float s = 0.f, q = 0.f;
#pragma unroll
  for (int c = 0; c < 3; ++c) {
    int ch = c * 64 + lane;          // bf16x4 chunk 0..191
    bf16x4 a = y0p[ch], b = y1p[ch];
#pragma unroll
    for (int j = 0; j < 4; ++j) {
      float t = ((float)a[j] + (float)b[j]) * inv_rs;
      if (HAS_BIAS) t += yb[ch * 4 + j];
      v[c * 4 + j] = t; s += t; q += t * t;
    }
  }
#pragma unroll
  for (int o = 1; o < 64; o <<= 1) { s += __shfl_xor(s, o); q += __shfl_xor(q, o); }
  const float mu  = s * (1.0f / EMBED);
  const float var = q * (1.0f / EMBED) - mu * mu;
  const float inv = rsqrtf(var + 1e-5f);
  const bf16x4* xp = (const bf16x4*)(xres + row * EMBED);
#pragma unroll
  for (int c = 0; c < 3; ++c) {
    int ch = c * 64 + lane;
    bf16x4 xv = xp[ch];
    float4 o4; bf16x4 ob;
#pragma unroll
    for (int j = 0; j < 4; ++j) {
      int col = ch * 4 + j;
      float o = (v[c * 4 + j] - mu) * inv * g[col] + beta[col] + (float)xv[j];
      ((float*)&o4)[j] = o;
      ob[j] = (bf16)o;
    }
    if (OUT_F32) ((float4*)(out + row * EMBED))[ch] = o4;
    else         ((bf16x4*)(outb + row * EMBED))[ch] = ob;
  }
}

// ---------------------------------------------------------------- launcher
extern "C" void kernel_launch(void* const* d_in, const int* in_sizes, int n_in,
                              void* d_out, int out_size, void* d_ws, size_t ws_size,
                              hipStream_t stream) {
  const float* x   = (const float*)d_in[0];
  const float* Wq  = (const float*)d_in[1];
  const float* bq  = (const float*)d_in[2];
  const float* Wk  = (const float*)d_in[3];
  const float* bk  = (const float*)d_in[4];
  const float* Wv  = (const float*)d_in[5];
  const float* bv  = (const float*)d_in[6];
  const float* W1  = (const float*)d_in[7];
  const float* b1  = (const float*)d_in[8];
  const float* W2  = (const float*)d_in[9];
  const float* b2  = (const float*)d_in[10];
  const float* g1  = (const float*)d_in[11];
  const float* be1 = (const float*)d_in[12];
  const float* g2  = (const float*)d_in[13];
  const float* be2 = (const float*)d_in[14];

  // workspace layout (bytes, peak 159,776,768 — proven)
  char* ws = (char*)d_ws;
  bf16*  xb    = (bf16*)(ws + 0);            // 12,582,912
  bf16*  WqkvT = (bf16*)(ws + 12582912);     //  3,538,944  [2304][768]
  bf16*  W1T   = (bf16*)(ws + 16121856);     //  4,718,592
  bf16*  W2T   = (bf16*)(ws + 20840448);     //  4,718,592
  bf16*  x1b   = (bf16*)(ws + 25559040);     // 12,582,912  (x1 residual, bf16)
  bf16*  Qs    = (bf16*)(ws + 38141952);     // 12,582,912
  bf16*  Kb    = (bf16*)(ws + 50724864);     // 12,582,912
  bf16*  VT    = (bf16*)(ws + 63307776);     // 12,582,912
  float* rowsum= (float*)(ws + 75890688);    //     32,768
  bf16*  P     = (bf16*)(ws + 92667904);     // 16,777,216  (unnormalized exp scores)
  bf16*  att0  = (bf16*)(ws + 109445120);    // 12,582,912  PV partial 0 (bf16)
  bf16*  att1  = (bf16*)(ws + 134610944);    // 12,582,912  PV partial 1 (bf16)
  bf16*  H     = (bf16*)(ws + 38141952);     // 50,331,648 over Qs..P-area (dead by FFN1)
  bf16*  F0    = (bf16*)(ws + 109445120);    // over att0 (dead by FFN2)
  bf16*  F1    = (bf16*)(ws + 134610944);    // over att1 (dead by FFN2)

  const float scale = 0.036084391824351615f;  // 768^-0.5

  // fused prep: all 5 transposes + x->bf16 + rowsum zero (one launch)
  prep_kernel<<<12480, 256, 0, stream>>>(Wq, Wk, Wv, W1, W2, WqkvT, W1T, W2T, x, xb, rowsum);

  // fused QKV projection (scale folded into Q region)
  gemm_nt<MODE_QKV><<<dim3(2304 / 128, ROWS / 128, 1), 256, 0, stream>>>(
      xb, WqkvT, Qs, bq, scale, ROWS, 2304, EMBED, EMBED, EMBED, 0, 0, 0, Kb, VT, bk, bv);

  // P~ = exp(Qs . K^T), rowsums accumulated atomically (softmax fused; no max-sub)
  gemm_nt<MODE_EXP><<<dim3(SEQ / 128, SEQ / 128, BATCH), 256, 0, stream>>>(
      Qs, Kb, P, nullptr, 1.f, SEQ, SEQ, EMBED, EMBED, EMBED,
      (long)SEQ * EMBED, (long)SEQ * EMBED, (long)SEQ * SEQ,
      rowsum, nullptr, nullptr, nullptr);

  // att~ = P~ . V  (batched, split-K=2, bf16 partials)
  gemm_nt<MODE_SPLIT><<<dim3(EMBED / 128, SEQ / 128, BATCH * 2), 256, 0, stream>>>(
      P, VT, att0, nullptr, 1.f, SEQ, EMBED, SEQ / 2, SEQ, SEQ,
      (long)SEQ * SEQ, (long)EMBED * SEQ, (long)SEQ * EMBED, att1, nullptr, nullptr, nullptr);

  // x1 = xb + LN((att0+att1)/rowsum)  -> bf16
  add_ln_kernel<1, 0, 0><<<ROWS / 4, 256, 0, stream>>>(
      xb, att0, att1, nullptr, rowsum, g1, be1, nullptr, x1b);

  // FFN1 (GELU, bf16 out)
  gemm_nt<MODE_GELU><<<dim3(FF / 128, ROWS / 128, 1), 256, 0, stream>>>(
      x1b, W1T, H, b1, 1.f, ROWS, FF, EMBED, EMBED, EMBED, 0, 0, 0,
      nullptr, nullptr, nullptr, nullptr);

  // FFN2 (split-K=2: K=1536 per split, bias deferred to LN stage, bf16 partials)
  gemm_nt<MODE_SPLIT><<<dim3(EMBED / 128, ROWS / 128, 2), 256, 0, stream>>>(
      H, W2T, F0, nullptr, 1.f, ROWS, EMBED, FF / 2, FF, FF, 0, 0, 0,
      F1, nullptr, nullptr, nullptr);

  // out = x1b + LN(F0+F1+b2)  -> fp32
  add_ln_kernel<0, 1, 1><<<ROWS / 4, 256, 0, stream>>>(
      x1b, F0, F1, b2, nullptr, g2, be2, (float*)d_out, nullptr);
}

// Round 4
// 325.674 us; speedup vs baseline: 1.2133x; 1.1950x over previous
//
#include <hip/hip_runtime.h>
#include <cstdint>
#include <cstddef>

typedef __bf16 bf16;
typedef __bf16 bf16x8 __attribute__((ext_vector_type(8)));
typedef __bf16 bf16x4 __attribute__((ext_vector_type(4)));
typedef float  f32x4  __attribute__((ext_vector_type(4)));

#define EMBED 768
#define FF    3072
#define SEQ   1024
#define BATCH 8
#define ROWS  (BATCH * SEQ)   // 8192

// ---------------- fused prep: 5 weight transposes (fp32 [K][N] -> bf16 [N][K]),
// x -> bf16, rowsum zero. Flat grid regions:
//   [0,1728)    : Wq/Wk/Wv -> WqkvT   (3 x 24x24 tiles of 32x32)
//   [1728,4032) : W1 -> W1T           (96x24 tiles)
//   [4032,6336) : W2 -> W2T           (24x96 tiles)
//   [6336,12480): cvt x (float4 chunks) + rowsum zero
__global__ void prep_kernel(const float* __restrict__ Wq, const float* __restrict__ Wk,
                            const float* __restrict__ Wv, const float* __restrict__ W1,
                            const float* __restrict__ W2, bf16* __restrict__ WqkvT,
                            bf16* __restrict__ W1T, bf16* __restrict__ W2T,
                            const float* __restrict__ x, bf16* __restrict__ xb,
                            float* __restrict__ rowsum) {
  const int id = blockIdx.x;
  const int tid = threadIdx.x;
  if (id >= 6336) {
    int i = (id - 6336) * 256 + tid;          // float4 chunk of x
    float4 v = ((const float4*)x)[i];
    bf16x4 o;
    o.x = (bf16)v.x; o.y = (bf16)v.y; o.z = (bf16)v.z; o.w = (bf16)v.w;
    ((bf16x4*)xb)[i] = o;
    if (i < ROWS) rowsum[i] = 0.f;
    return;
  }
  __shared__ float tile[32][33];
  const float* src; bf16* dst; int K, N, nbt, kbt;
  if (id < 1728) {
    int w = id / 576, t = id % 576;
    src = (w == 0) ? Wq : (w == 1 ? Wk : Wv);
    dst = WqkvT + (size_t)w * EMBED * EMBED;
    K = EMBED; N = EMBED; nbt = t % 24; kbt = t / 24;
  } else if (id < 4032) {
    int t = id - 1728;
    src = W1; dst = W1T; K = EMBED; N = FF; nbt = t % 96; kbt = t / 96;
  } else {
    int t = id - 4032;
    src = W2; dst = W2T; K = FF; N = EMBED; nbt = t % 24; kbt = t / 24;
  }
  const int tx = tid & 31, ty = tid >> 5;     // (32,8)
  int nb = nbt * 32, kb = kbt * 32;
  for (int i = ty; i < 32; i += 8)
    tile[i][tx] = src[(size_t)(kb + i) * N + nb + tx];
  __syncthreads();
  for (int i = ty; i < 32; i += 8)
    dst[(size_t)(nb + i) * K + kb + tx] = (bf16)tile[tx][i];
}

// ---------------------------------------------------------------- MFMA NT GEMM
// C[M][N] = A[M][K] . BT[N][K]^T, bf16 in. BK=64, 32 KB LDS, single-buffered,
// 2-barrier K-loop — round-0 proven best (78 us FFN1-class, ~500 TF). The
// structure hides its vmcnt drain via INTER-BLOCK TLP (~2.4 blocks/CU, m114);
// every occupancy-reducing "pipeline" edit lost more than it gained.
// CLOSED EXPERIMENTS (do not revisit): R3 dbuf 64 KB 2-barrier; R5 BK=32;
// R8 1-barrier dbuf 32 KB (65->84); R9 256^2 dbuf counted-vmcnt serial phases
// (115 us, 1 blk/CU); R10 256^2 interleaved quadrants (99 us); R11 128^2
// 2-phase stage-early dbuf (87 us, FETCH +42% L2 thrash). K-loop sync
// structure is exhausted at HIP level per m131-141; only a verified 8-phase
// port (exact m201 file) could beat it, and blind reconstructions race/stall.
// R12: XCD-aware remap extended to batched (z>1) grids — bijective chunked
// map (m204) so each XCD owns a contiguous logical range: EXP chunk = one
// batch (Qs+Kb = 3 MB fits 4 MB XCD-L2), PV chunk = one batch both splits,
// FFN2 chunk = half-split W2T panel. z==1 path byte-identical to round-0.
enum { MODE_QKV = 0, MODE_EXP = 1, MODE_F32 = 2, MODE_GELU = 3, MODE_SPLIT = 4 };

template <int MODE>
__global__ void gemm_nt(const bf16* __restrict__ A, const bf16* __restrict__ B,
                        void* __restrict__ C, const float* __restrict__ bias, float alpha,
                        int M, int N, int K, int lda, int ldb, long sA, long sB, long sC,
                        void* __restrict__ C2, void* __restrict__ C3,
                        const float* __restrict__ bias2, const float* __restrict__ bias3) {
  __shared__ bf16 sAl[128 * 64];   // 16 KB
  __shared__ bf16 sBl[128 * 64];
  const int tid  = threadIdx.x;
  const int lane = tid & 63;
  const int wave = tid >> 6;
  const int wm   = (wave >> 1) * 64;
  const int wn   = (wave & 1) * 64;
  const int quad = lane >> 4;
  const int l15  = lane & 15;
  const int l7   = lane & 7;

  int bx = blockIdx.x, by = blockIdx.y, bz = blockIdx.z;
  if (gridDim.z == 1) {
    // round-0 proven 2D swizzle: XCD g owns gy/8 consecutive y-tiles, all x.
    if ((gridDim.y & 7) == 0) {
      const int gx = gridDim.x, gy = gridDim.y;
      const int b  = by * gx + bx;
      const int xcd = b & 7, s = b >> 3;
      bx = s % gx;
      by = xcd * (gy >> 3) + s / gx;
    }
  } else {
    // R12: bijective chunked remap for batched grids. HW round-robins flat
    // block id across XCDs (id%8); executing logical tile
    // (f%8)*(nblk/8)+f/8 gives each XCD a contiguous logical chunk ->
    // per-XCD L2 keeps one batch's panels resident.
    const int gx = gridDim.x, gxy = gx * gridDim.y;
    const int nblk = gxy * gridDim.z;
    if ((nblk & 7) == 0) {
      int f = bz * gxy + by * gx + bx;
      int logical = (f & 7) * (nblk >> 3) + (f >> 3);
      bz = logical / gxy;
      int rem = logical - bz * gxy;
      by = rem / gx;
      bx = rem - by * gx;
    }
  }

  int split = 0, batch = bz;
  if constexpr (MODE == MODE_SPLIT) { split = bz & 1; batch = bz >> 1; }

  const bf16* Ab = A + (size_t)batch * sA + (size_t)split * K + (size_t)by * 128 * lda;
  const bf16* Bb = B + (size_t)batch * sB + (size_t)split * K + (size_t)bx * 128 * ldb;

  f32x4 acc[4][4] = {};

  for (int k0 = 0; k0 < K; k0 += 64) {
#pragma unroll
    for (int c = 0; c < 4; ++c) {
      int f   = c * 256 + tid;                 // 0..1023 chunk of 16B
      int row = f >> 3;                        // 0..127
      int col = ((f & 7) ^ (row & 7)) * 8;     // swizzled bf16 col within 64-wide stage
      __builtin_amdgcn_global_load_lds(
          (__attribute__((address_space(1))) void*)(Ab + (size_t)row * lda + k0 + col),
          (__attribute__((address_space(3))) void*)(sAl + (size_t)(c * 256 + wave * 64) * 8),
          16, 0, 0);
      __builtin_amdgcn_global_load_lds(
          (__attribute__((address_space(1))) void*)(Bb + (size_t)row * ldb + k0 + col),
          (__attribute__((address_space(3))) void*)(sBl + (size_t)(c * 256 + wave * 64) * 8),
          16, 0, 0);
    }
    __syncthreads();
#pragma unroll
    for (int kk = 0; kk < 2; ++kk) {
      const int ga = (((kk << 2) | quad) ^ l7) * 8;   // swizzled granule for this lane
      bf16x8 af[4], bfr[4];
#pragma unroll
      for (int t = 0; t < 4; ++t) {
        af[t]  = *(const bf16x8*)&sAl[(wm + t * 16 + l15) * 64 + ga];
        bfr[t] = *(const bf16x8*)&sBl[(wn + t * 16 + l15) * 64 + ga];
      }
#pragma unroll
      for (int mt = 0; mt < 4; ++mt)
#pragma unroll
        for (int nt = 0; nt < 4; ++nt)
          acc[mt][nt] = __builtin_amdgcn_mfma_f32_16x16x32_bf16(af[mt], bfr[nt], acc[mt][nt], 0, 0, 0);
    }
    __syncthreads();
  }

  // epilogue: D row = quad*4 + r (+16*mt), col = l15 (+16*nt)   [m89-verified]
  const size_t mbase = (size_t)by * 128 + wm + quad * 4;

  if constexpr (MODE == MODE_QKV) {
    const int region = (bx * 128) / 768;     // 0=Q 1=K 2=V (768 % 128 == 0)
    const int nloc0  = bx * 128 - region * 768 + wn + l15;
    const float* bs  = (region == 0) ? bias : (region == 1 ? bias2 : bias3);
    const float  a   = (region == 0) ? alpha : 1.0f;
    if (region == 2) {
      // V^T per batch: VT[b][n][s]; 4 r-values are s-consecutive, same n ->
      // one bf16x4 store (16 x 8 B instead of 64 x 2 B scattered).
#pragma unroll
      for (int mt = 0; mt < 4; ++mt)
#pragma unroll
        for (int nt = 0; nt < 4; ++nt) {
          size_t m0 = mbase + mt * 16;          // %4 == 0, no batch crossing
          int nl = nloc0 + nt * 16;
          bf16x4 pk;
#pragma unroll
          for (int r = 0; r < 4; ++r) pk[r] = (bf16)(acc[mt][nt][r] + bs[nl]);
          size_t b = m0 >> 10, s = m0 & 1023;
          *(bf16x4*)&((bf16*)C3)[b * ((size_t)EMBED * SEQ) + (size_t)nl * SEQ + s] = pk;
        }
    } else {
#pragma unroll
      for (int mt = 0; mt < 4; ++mt)
#pragma unroll
        for (int r = 0; r < 4; ++r) {
          size_t m = mbase + mt * 16 + r;
#pragma unroll
          for (int nt = 0; nt < 4; ++nt) {
            int nl  = nloc0 + nt * 16;
            float v = (acc[mt][nt][r] + bs[nl]) * a;
            if (region == 0) ((bf16*)C )[m * EMBED + nl] = (bf16)v;
            else             ((bf16*)C2)[m * EMBED + nl] = (bf16)v;
          }
        }
    }
  } else if constexpr (MODE == MODE_EXP) {
    // P~ = exp(score) bf16; rowsum[batch*SEQ+m] += sum_n exp  (C2 = rowsum)
    float* rowsum = (float*)C2;
#pragma unroll
    for (int mt = 0; mt < 4; ++mt)
#pragma unroll
      for (int r = 0; r < 4; ++r) {
        size_t m = mbase + mt * 16 + r;
        float part = 0.f;
#pragma unroll
        for (int nt = 0; nt < 4; ++nt) {
          size_t n = (size_t)bx * 128 + wn + l15 + nt * 16;
          float e = __expf(acc[mt][nt][r]);
          part += e;
          ((bf16*)C)[(size_t)batch * sC + m * N + n] = (bf16)e;
        }
        part += __shfl_xor(part, 1);
        part += __shfl_xor(part, 2);
        part += __shfl_xor(part, 4);
        part += __shfl_xor(part, 8);
        if (l15 == 0) atomicAdd(&rowsum[(size_t)batch * SEQ + m], part);
      }
  } else if constexpr (MODE == MODE_SPLIT) {
    bf16* Cp = (bf16*)(split ? C2 : C) + (size_t)batch * sC;
#pragma unroll
    for (int mt = 0; mt < 4; ++mt)
#pragma unroll
      for (int r = 0; r < 4; ++r) {
        size_t m = mbase + mt * 16 + r;
#pragma unroll
        for (int nt = 0; nt < 4; ++nt) {
          size_t n = (size_t)bx * 128 + wn + l15 + nt * 16;
          Cp[m * N + n] = (bf16)acc[mt][nt][r];
        }
      }
  } else {
    const size_t nbase = (size_t)bx * 128 + wn + l15;
#pragma unroll
    for (int mt = 0; mt < 4; ++mt)
#pragma unroll
      for (int r = 0; r < 4; ++r) {
        size_t m = mbase + mt * 16 + r;
#pragma unroll
        for (int nt = 0; nt < 4; ++nt) {
          size_t n = nbase + nt * 16;
          float v = acc[mt][nt][r];
          if (bias) v += bias[n];
          v *= alpha;
          if constexpr (MODE == MODE_GELU) {
            // tanh-form GELU; raw rcp (no NR) — err ~1e-5 rel, safe at exp=0/inf
            float y = 1.5957691216f * (v + 0.044715f * v * v * v);
            float g = v * __builtin_amdgcn_rcpf(1.0f + __expf(-y));
            ((bf16*)C)[m * (size_t)N + n] = (bf16)g;
          } else {
            ((float*)C)[(size_t)batch * sC + m * (size_t)N + n] = v;
          }
        }
      }
  }
}

// ---- per-wave row LN: out = xres + LN((y0+y1)*inv_rs + yb)*g + beta
// block = 256 thr = 4 waves, one row/wave, no LDS, no __syncthreads.
template <int HAS_RS, int HAS_BIAS, int OUT_F32>
__global__ void add_ln_kernel(const bf16* __restrict__ xres, const bf16* __restrict__ y0,
                              const bf16* __restrict__ y1, const float* __restrict__ yb,
                              const float* __restrict__ rowsum,
                              const float* __restrict__ g, const float* __restrict__ beta,
                              float* __restrict__ out, bf16* __restrict__ outb) {
  const int lane = threadIdx.x & 63;
  const int wv   = threadIdx.x >> 6;
  const size_t row = (size_t)blockIdx.x * 4 + wv;
  const float inv_rs = HAS_RS ? (1.0f / rowsum[row]) : 1.0f;
  const bf16x4* y0p = (const bf16x4*)(y0 + row * EMBED);
  const bf16x4* y1p = (const bf16x4*)(y1 + row * EMBED);
  float v[12];
  float s = 0.f, q = 0.f;
#pragma unroll
  for (int c = 0; c < 3; ++c) {
    int ch = c * 64 + lane;          // bf16x4 chunk 0..191
    bf16x4 a = y0p[ch], b = y1p[ch];
#pragma unroll
    for (int j = 0; j < 4; ++j) {
      float t = ((float)a[j] + (float)b[j]) * inv_rs;
      if (HAS_BIAS) t += yb[ch * 4 + j];
      v[c * 4 + j] = t; s += t; q += t * t;
    }
  }
#pragma unroll
  for (int o = 1; o < 64; o <<= 1) { s += __shfl_xor(s, o); q += __shfl_xor(q, o); }
  const float mu  = s * (1.0f / EMBED);
  const float var = q * (1.0f / EMBED) - mu * mu;
  const float inv = rsqrtf(var + 1e-5f);
  const bf16x4* xp = (const bf16x4*)(xres + row * EMBED);
#pragma unroll
  for (int c = 0; c < 3; ++c) {
    int ch = c * 64 + lane;
    bf16x4 xv = xp[ch];
    float4 o4; bf16x4 ob;
#pragma unroll
    for (int j = 0; j < 4; ++j) {
      int col = ch * 4 + j;
      float o = (v[c * 4 + j] - mu) * inv * g[col] + beta[col] + (float)xv[j];
      ((float*)&o4)[j] = o;
      ob[j] = (bf16)o;
    }
    if (OUT_F32) ((float4*)(out + row * EMBED))[ch] = o4;
    else         ((bf16x4*)(outb + row * EMBED))[ch] = ob;
  }
}

// ---------------------------------------------------------------- launcher
extern "C" void kernel_launch(void* const* d_in, const int* in_sizes, int n_in,
                              void* d_out, int out_size, void* d_ws, size_t ws_size,
                              hipStream_t stream) {
  const float* x   = (const float*)d_in[0];
  const float* Wq  = (const float*)d_in[1];
  const float* bq  = (const float*)d_in[2];
  const float* Wk  = (const float*)d_in[3];
  const float* bk  = (const float*)d_in[4];
  const float* Wv  = (const float*)d_in[5];
  const float* bv  = (const float*)d_in[6];
  const float* W1  = (const float*)d_in[7];
  const float* b1  = (const float*)d_in[8];
  const float* W2  = (const float*)d_in[9];
  const float* b2  = (const float*)d_in[10];
  const float* g1  = (const float*)d_in[11];
  const float* be1 = (const float*)d_in[12];
  const float* g2  = (const float*)d_in[13];
  const float* be2 = (const float*)d_in[14];

  // workspace layout (bytes, peak 159,776,768 — proven)
  char* ws = (char*)d_ws;
  bf16*  xb    = (bf16*)(ws + 0);            // 12,582,912
  bf16*  WqkvT = (bf16*)(ws + 12582912);     //  3,538,944  [2304][768]
  bf16*  W1T   = (bf16*)(ws + 16121856);     //  4,718,592
  bf16*  W2T   = (bf16*)(ws + 20840448);     //  4,718,592
  bf16*  x1b   = (bf16*)(ws + 25559040);     // 12,582,912  (x1 residual, bf16)
  bf16*  Qs    = (bf16*)(ws + 38141952);     // 12,582,912
  bf16*  Kb    = (bf16*)(ws + 50724864);     // 12,582,912
  bf16*  VT    = (bf16*)(ws + 63307776);     // 12,582,912
  float* rowsum= (float*)(ws + 75890688);    //     32,768
  bf16*  P     = (bf16*)(ws + 92667904);     // 16,777,216  (unnormalized exp scores)
  bf16*  att0  = (bf16*)(ws + 109445120);    // 12,582,912  PV partial 0 (bf16)
  bf16*  att1  = (bf16*)(ws + 134610944);    // 12,582,912  PV partial 1 (bf16)
  bf16*  H     = (bf16*)(ws + 38141952);     // 50,331,648 over Qs..P-area (dead by FFN1)
  bf16*  F0    = (bf16*)(ws + 109445120);    // over att0 (dead by FFN2)
  bf16*  F1    = (bf16*)(ws + 134610944);    // over att1 (dead by FFN2)

  const float scale = 0.036084391824351615f;  // 768^-0.5

  // fused prep: all 5 transposes + x->bf16 + rowsum zero (one launch)
  prep_kernel<<<12480, 256, 0, stream>>>(Wq, Wk, Wv, W1, W2, WqkvT, W1T, W2T, x, xb, rowsum);

  // fused QKV projection (scale folded into Q region)
  gemm_nt<MODE_QKV><<<dim3(2304 / 128, ROWS / 128, 1), 256, 0, stream>>>(
      xb, WqkvT, Qs, bq, scale, ROWS, 2304, EMBED, EMBED, EMBED, 0, 0, 0, Kb, VT, bk, bv);

  // P~ = exp(Qs . K^T), rowsums accumulated atomically (softmax fused; no max-sub)
  gemm_nt<MODE_EXP><<<dim3(SEQ / 128, SEQ / 128, BATCH), 256, 0, stream>>>(
      Qs, Kb, P, nullptr, 1.f, SEQ, SEQ, EMBED, EMBED, EMBED,
      (long)SEQ * EMBED, (long)SEQ * EMBED, (long)SEQ * SEQ,
      rowsum, nullptr, nullptr, nullptr);

  // att~ = P~ . V  (batched, split-K=2, bf16 partials)
  gemm_nt<MODE_SPLIT><<<dim3(EMBED / 128, SEQ / 128, BATCH * 2), 256, 0, stream>>>(
      P, VT, att0, nullptr, 1.f, SEQ, EMBED, SEQ / 2, SEQ, SEQ,
      (long)SEQ * SEQ, (long)EMBED * SEQ, (long)SEQ * EMBED, att1, nullptr, nullptr, nullptr);

  // x1 = xb + LN((att0+att1)/rowsum)  -> bf16
  add_ln_kernel<1, 0, 0><<<ROWS / 4, 256, 0, stream>>>(
      xb, att0, att1, nullptr, rowsum, g1, be1, nullptr, x1b);

  // FFN1 (GELU, bf16 out)
  gemm_nt<MODE_GELU><<<dim3(FF / 128, ROWS / 128, 1), 256, 0, stream>>>(
      x1b, W1T, H, b1, 1.f, ROWS, FF, EMBED, EMBED, EMBED, 0, 0, 0,
      nullptr, nullptr, nullptr, nullptr);

  // FFN2 (split-K=2: K=1536 per split, bias deferred to LN stage, bf16 partials)
  gemm_nt<MODE_SPLIT><<<dim3(EMBED / 128, ROWS / 128, 2), 256, 0, stream>>>(
      H, W2T, F0, nullptr, 1.f, ROWS, EMBED, FF / 2, FF, FF, 0, 0, 0,
      F1, nullptr, nullptr, nullptr);

  // out = x1b + LN(F0+F1+b2)  -> fp32
  add_ln_kernel<0, 1, 1><<<ROWS / 4, 256, 0, stream>>>(
      x1b, F0, F1, b2, nullptr, g2, be2, (float*)d_out, nullptr);
}